// Round 5
// baseline (542.003 us; speedup 1.0000x reference)
//
#include <hip/hip_runtime.h>

typedef __bf16 bf16;
typedef __attribute__((ext_vector_type(8))) __bf16 bf16x8;
typedef __attribute__((ext_vector_type(4))) __bf16 bf16x4;
typedef __attribute__((ext_vector_type(4))) float f32x4;
typedef __attribute__((ext_vector_type(16))) float f32x16;

#define MFMA16(a, b, c) __builtin_amdgcn_mfma_f32_16x16x32_bf16((a), (b), (c), 0, 0, 0)
#define MFMA32(a, b, c) __builtin_amdgcn_mfma_f32_32x32x16_bf16((a), (b), (c), 0, 0, 0)

__device__ __forceinline__ void gload16(const void* g, void* lds) {
  __builtin_amdgcn_global_load_lds(
      (__attribute__((address_space(1))) unsigned int*)(unsigned long long)g,
      (__attribute__((address_space(3))) unsigned int*)lds, 16, 0, 0);
}

// ---------------- cast X (fp32 -> bf16) ----------------
__global__ void __launch_bounds__(256) cast_x_kernel(const float* __restrict__ X,
                                                     bf16* __restrict__ Xb) {
  int i = (blockIdx.x * 256 + threadIdx.x) * 4;
  f32x4 v = *(const f32x4*)(X + i);
  bf16x4 o;
  o[0] = (bf16)v[0]; o[1] = (bf16)v[1]; o[2] = (bf16)v[2]; o[3] = (bf16)v[3];
  *(bf16x4*)(Xb + i) = o;
}

// ---------------- transpose + cast weight: WT[n][k] = W[k][n] ----------------
__global__ void __launch_bounds__(256) transpose_w_kernel(const float* __restrict__ W,
                                                          bf16* __restrict__ WT) {
  __shared__ float tile[64][65];
  int n0 = (blockIdx.x & 31) * 64;
  int k0 = (blockIdx.x >> 5) * 64;
  int tid = threadIdx.x;
  int r = tid >> 4;
  int c4 = (tid & 15) * 4;
#pragma unroll
  for (int i = 0; i < 4; ++i) {
    f32x4 v = *(const f32x4*)(W + (size_t)(k0 + r + i * 16) * 2048 + n0 + c4);
    tile[r + i * 16][c4 + 0] = v[0];
    tile[r + i * 16][c4 + 1] = v[1];
    tile[r + i * 16][c4 + 2] = v[2];
    tile[r + i * 16][c4 + 3] = v[3];
  }
  __syncthreads();
#pragma unroll
  for (int i = 0; i < 4; ++i) {
    int n = r + i * 16;
    bf16x4 o;
    o[0] = (bf16)tile[c4 + 0][n];
    o[1] = (bf16)tile[c4 + 1][n];
    o[2] = (bf16)tile[c4 + 2][n];
    o[3] = (bf16)tile[c4 + 3][n];
    *(bf16x4*)(WT + (size_t)(n0 + n) * 2048 + k0 + c4) = o;
  }
}

// ---------------- 256x256 8-phase GEMM core (BK=64, 32x32x16 MFMA) ----------------
// 8 waves (2M x 4N), per-wave C 128x64 = f32x16 acc[4][2]. LDS 128KB:
// [2 buf][A,B][2 khalf][256 rows][32 cols bf16] (16KB units). Per phase:
// 6 ds_read_b128 + stage one k-half (2 gload_lds) + barrier + lgkmcnt(0)
// + setprio(1) + 8 MFMA + setprio(0) (+ vmcnt(4) once per K-tile) + barrier.
// Swizzle: LDS granule (16B) = nominal ^ ((row>>1)&3); staged via pre-swizzled
// global source + linear dest, read with same XOR (both-sides rule).
__device__ __forceinline__ void gemm256_core(const bf16* __restrict__ Ag,
                                             const bf16* __restrict__ Bg,
                                             char* lds, f32x16 (&acc)[4][2]) {
  const int tid = threadIdx.x;
  const int lane = tid & 63, wid = tid >> 6;
  const int l31 = lane & 31, l5 = lane >> 5;
  const int wm = wid >> 2, wn = wid & 3;

  // staging: dest (linear in 16KB half) byte = r*8192 + wid*1024 + lane*16
  //   -> row = r*128 + wid*16 + (lane>>2), granule = lane&3
  // pre-swizzled source granule = (lane&3) ^ ((row>>1)&3) = (lane&3)^((lane>>3)&3)
  const int srow = wid * 16 + (lane >> 2);
  const int sg = ((lane & 3) ^ ((lane >> 3) & 3)) * 8;
  const bf16* gA = Ag + (size_t)srow * 2048 + sg;
  const bf16* gB = Bg + (size_t)srow * 2048 + sg;
  char* sBase = lds + wid * 1024;

  // read-side: row = (region)+l31, nominal granule = 2*(kk&1)+l5, ^ (row>>1)&3
  const int g01 = ((l5) ^ ((l31 >> 1) & 3)) * 16;       // kk even
  const int g23 = ((2 + l5) ^ ((l31 >> 1) & 3)) * 16;   // kk odd
  const char* aB = lds + (wm * 128 + l31) * 64;
  const char* bB = lds + 32768 + (wn * 64 + l31) * 64;

#define STAGE(ab_, buf_, kh_, T_)                                        \
  {                                                                      \
    const bf16* s_ = ((ab_) ? gB : gA) + (size_t)(T_) * 64 + (kh_) * 32; \
    char* d_ = sBase + (buf_) * 65536 + (ab_) * 32768 + (kh_) * 16384;   \
    gload16(s_, d_);                                                     \
    gload16(s_ + (size_t)128 * 2048, d_ + 8192);                         \
  }

#define LD6(buf_, kk_)                                                   \
  {                                                                      \
    const int kb_ = (buf_) * 65536 + ((kk_) >> 1) * 16384;               \
    const int gb_ = ((kk_) & 1) ? g23 : g01;                             \
    af0 = *(const bf16x8*)(aB + kb_ + 0 * 2048 + gb_);                   \
    af1 = *(const bf16x8*)(aB + kb_ + 1 * 2048 + gb_);                   \
    af2 = *(const bf16x8*)(aB + kb_ + 2 * 2048 + gb_);                   \
    af3 = *(const bf16x8*)(aB + kb_ + 3 * 2048 + gb_);                   \
    bq0 = *(const bf16x8*)(bB + kb_ + 0 * 2048 + gb_);                   \
    bq1 = *(const bf16x8*)(bB + kb_ + 1 * 2048 + gb_);                   \
  }

#define MFMA_CLUSTER()                                                   \
  __builtin_amdgcn_s_barrier();                                          \
  asm volatile("s_waitcnt lgkmcnt(0)" ::: "memory");                     \
  __builtin_amdgcn_sched_barrier(0);                                     \
  __builtin_amdgcn_s_setprio(1);                                         \
  acc[0][0] = MFMA32(af0, bq0, acc[0][0]);                               \
  acc[0][1] = MFMA32(af0, bq1, acc[0][1]);                               \
  acc[1][0] = MFMA32(af1, bq0, acc[1][0]);                               \
  acc[1][1] = MFMA32(af1, bq1, acc[1][1]);                               \
  acc[2][0] = MFMA32(af2, bq0, acc[2][0]);                               \
  acc[2][1] = MFMA32(af2, bq1, acc[2][1]);                               \
  acc[3][0] = MFMA32(af3, bq0, acc[3][0]);                               \
  acc[3][1] = MFMA32(af3, bq1, acc[3][1]);                               \
  __builtin_amdgcn_s_setprio(0);

  bf16x8 af0, af1, af2, af3, bq0, bq1;

  // prologue: tile0 all 4 halves + tile1 k0 halves; wait tile0 (4 loads in flight)
  STAGE(0, 0, 0, 0) STAGE(1, 0, 0, 0)
  STAGE(0, 0, 1, 0) STAGE(1, 0, 1, 0)
  STAGE(0, 1, 0, 1) STAGE(1, 1, 0, 1)
  asm volatile("s_waitcnt vmcnt(4)" ::: "memory");
  __builtin_amdgcn_s_barrier();

  for (int t = 0; t < 32; t += 2) {
    // ---- K-tile t (buf 0) ----
    LD6(0, 0) if (t + 1 < 32) STAGE(0, 1, 1, t + 1)
    MFMA_CLUSTER() __builtin_amdgcn_s_barrier();
    LD6(0, 1) if (t + 1 < 32) STAGE(1, 1, 1, t + 1)
    MFMA_CLUSTER() __builtin_amdgcn_s_barrier();
    LD6(0, 2) if (t + 2 < 32) STAGE(0, 0, 0, t + 2)
    MFMA_CLUSTER() __builtin_amdgcn_s_barrier();
    LD6(0, 3) if (t + 2 < 32) STAGE(1, 0, 0, t + 2)
    MFMA_CLUSTER()
    if (t + 2 < 32) { asm volatile("s_waitcnt vmcnt(4)" ::: "memory"); }
    else           { asm volatile("s_waitcnt vmcnt(0)" ::: "memory"); }
    __builtin_amdgcn_s_barrier();
    // ---- K-tile t+1 (buf 1) ----
    LD6(1, 0) if (t + 2 < 32) STAGE(0, 0, 1, t + 2)
    MFMA_CLUSTER() __builtin_amdgcn_s_barrier();
    LD6(1, 1) if (t + 2 < 32) STAGE(1, 0, 1, t + 2)
    MFMA_CLUSTER() __builtin_amdgcn_s_barrier();
    LD6(1, 2) if (t + 3 < 32) STAGE(0, 1, 0, t + 3)
    MFMA_CLUSTER() __builtin_amdgcn_s_barrier();
    LD6(1, 3) if (t + 3 < 32) STAGE(1, 1, 0, t + 3)
    MFMA_CLUSTER()
    if (t + 3 < 32) { asm volatile("s_waitcnt vmcnt(4)" ::: "memory"); }
    else           { asm volatile("s_waitcnt vmcnt(0)" ::: "memory"); }
    __builtin_amdgcn_s_barrier();
  }
#undef STAGE
#undef LD6
#undef MFMA_CLUSTER
}

// ---------------- QKV projection GEMM (256^2, 8-phase), scatter tile-major ----------------
__global__ void __launch_bounds__(512, 2) gemm_qkv_kernel(
    const bf16* __restrict__ Xb, const bf16* __restrict__ W0, const bf16* __restrict__ W1,
    const bf16* __restrict__ W2, bf16* __restrict__ q_t, bf16* __restrict__ k_t,
    bf16* __restrict__ v_t) {
  __shared__ char lds[131072];
  int bid = blockIdx.x;
  int xcd = bid & 7, idx = bid >> 3;          // 768 = 8 XCD chunks of 96
  int by = xcd * 4 + idx / 24, bx = idx % 24; // m-major within chunk for L2 reuse
  int which = bx >> 3;
  int m0 = by * 256, n0 = (bx & 7) * 256;
  const bf16* W = which == 0 ? W0 : (which == 1 ? W1 : W2);

  f32x16 acc[4][2] = {};
  gemm256_core(Xb + (size_t)m0 * 2048, W + (size_t)n0 * 2048, lds, acc);

  int lane = threadIdx.x & 63, wid = threadIdx.x >> 6;
  int l31 = lane & 31, l5 = lane >> 5;
  int wm = wid >> 2, wn = wid & 3;
  // C/D 32x32: col = lane&31, row = (reg&3) + 8*(reg>>2) + 4*(lane>>5)
#pragma unroll
  for (int mi = 0; mi < 4; ++mi) {
#pragma unroll
    for (int reg = 0; reg < 16; ++reg) {
      int m = m0 + wm * 128 + mi * 32 + (reg & 3) + ((reg >> 2) * 8) + l5 * 4;
      int b = m >> 12, s = m & 4095;
      int hg = s >> 6, wg = s & 63;
      int tt = ((hg >> 3) << 2) + (wg >> 4);
      int tn = ((hg & 7) << 4) + (wg & 15);
#pragma unroll
      for (int nj = 0; nj < 2; ++nj) {
        int n = n0 + wn * 64 + nj * 32 + l31;
        int h = n >> 6, hd = n & 63;
        float val = acc[mi][nj][reg];
        size_t base = ((size_t)(b * 32 + h) * 32 + tt);
        if (which == 0)
          q_t[(base * 128 + tn) * 64 + hd] = (bf16)(val * 0.125f);
        else if (which == 1)
          k_t[(base * 128 + tn) * 64 + hd] = (bf16)val;
        else
          v_t[(base * 64 + hd) * 128 + tn] = (bf16)val;
      }
    }
  }
}

// ---------------- output GEMM: out = o_bf @ Wo, fp32 row-major ----------------
__global__ void __launch_bounds__(512, 2) gemm_out_kernel(const bf16* __restrict__ A,
                                                          const bf16* __restrict__ W,
                                                          float* __restrict__ C) {
  __shared__ char lds[131072];
  int bid = blockIdx.x;
  int xcd = bid & 7, idx = bid >> 3;         // 256 = 8 chunks of 32
  int by = xcd * 4 + idx / 8, bx = idx & 7;
  int m0 = by * 256, n0 = bx * 256;

  f32x16 acc[4][2] = {};
  gemm256_core(A + (size_t)m0 * 2048, W + (size_t)n0 * 2048, lds, acc);

  int lane = threadIdx.x & 63, wid = threadIdx.x >> 6;
  int l31 = lane & 31, l5 = lane >> 5;
  int wm = wid >> 2, wn = wid & 3;
#pragma unroll
  for (int mi = 0; mi < 4; ++mi)
#pragma unroll
    for (int nj = 0; nj < 2; ++nj)
#pragma unroll
      for (int reg = 0; reg < 16; ++reg) {
        int m = m0 + wm * 128 + mi * 32 + (reg & 3) + ((reg >> 2) * 8) + l5 * 4;
        int n = n0 + wn * 64 + nj * 32 + l31;
        C[(size_t)m * 2048 + n] = acc[mi][nj][reg];
      }
}

// ---------------- block-sparse tile attention (unchanged, passing) ----------------
__global__ void __launch_bounds__(256) attn_kernel(const bf16* __restrict__ q_t,
                                                   const bf16* __restrict__ k_t,
                                                   const bf16* __restrict__ v_t,
                                                   bf16* __restrict__ o_bf) {
  __shared__ char Pl[128 * 256];  // P tile, bf16, XOR-swizzled rows of 256B
  int bid = blockIdx.x;
  int t = bid & 31, bh = bid >> 5;
  int h = bh & 31, b = bh >> 5;
  int tid = threadIdx.x, w = tid >> 6, lane = tid & 63;
  int g = lane >> 4, r16 = lane & 15;

  const size_t qoff = (size_t)bid * (128 * 64);
  bf16x8 qf[2][2];
#pragma unroll
  for (int mf = 0; mf < 2; ++mf)
#pragma unroll
    for (int kf = 0; kf < 2; ++kf)
      qf[mf][kf] = *(const bf16x8*)&q_t[qoff + (size_t)(w * 32 + mf * 16 + r16) * 64 + kf * 32 + g * 8];

  f32x4 oacc[2][4] = {};
  float mrun[2][4], lrun[2][4];
#pragma unroll
  for (int mf = 0; mf < 2; ++mf)
#pragma unroll
    for (int r = 0; r < 4; ++r) { mrun[mf][r] = -1e30f; lrun[mf][r] = 0.f; }

  int qh = t >> 2, qw = t & 3;
  int ch = qh < 1 ? 1 : (qh > 7 ? 7 : qh);
  int cw = qw < 1 ? 1 : (qw > 3 ? 3 : qw);

  for (int c = 0; c < 4; ++c) {
    int vt = (ch - 1 + (c >> 1)) * 4 + (cw - 1 + (c & 1));
    const bf16* Kt = k_t + ((size_t)bh * 32 + vt) * (128 * 64);
    const bf16* Vt = v_t + ((size_t)bh * 32 + vt) * (128 * 64);

    f32x4 s[2][8];
#pragma unroll
    for (int nf = 0; nf < 8; ++nf) {
      bf16x8 kf0 = *(const bf16x8*)&Kt[(nf * 16 + r16) * 64 + g * 8];
      bf16x8 kf1 = *(const bf16x8*)&Kt[(nf * 16 + r16) * 64 + 32 + g * 8];
#pragma unroll
      for (int mf = 0; mf < 2; ++mf) {
        f32x4 z = {};
        z = MFMA16(qf[mf][0], kf0, z);
        z = MFMA16(qf[mf][1], kf1, z);
        s[mf][nf] = z;
      }
    }

#pragma unroll
    for (int mf = 0; mf < 2; ++mf) {
#pragma unroll
      for (int r = 0; r < 4; ++r) {
        float mx = s[mf][0][r];
#pragma unroll
        for (int nf = 1; nf < 8; ++nf) mx = fmaxf(mx, s[mf][nf][r]);
        mx = fmaxf(mx, __shfl_xor(mx, 1));
        mx = fmaxf(mx, __shfl_xor(mx, 2));
        mx = fmaxf(mx, __shfl_xor(mx, 4));
        mx = fmaxf(mx, __shfl_xor(mx, 8));
        float mold = mrun[mf][r];
        float mnew = fmaxf(mold, mx);
        float sc = __expf(mold - mnew);
        mrun[mf][r] = mnew;
        float ps = 0.f;
#pragma unroll
        for (int nf = 0; nf < 8; ++nf) {
          float p = __expf(s[mf][nf][r] - mnew);
          s[mf][nf][r] = p;
          ps += p;
        }
        ps += __shfl_xor(ps, 1);
        ps += __shfl_xor(ps, 2);
        ps += __shfl_xor(ps, 4);
        ps += __shfl_xor(ps, 8);
        lrun[mf][r] = lrun[mf][r] * sc + ps;
#pragma unroll
        for (int hf = 0; hf < 4; ++hf) oacc[mf][hf][r] *= sc;
      }
    }

#pragma unroll
    for (int mf = 0; mf < 2; ++mf)
#pragma unroll
      for (int r = 0; r < 4; ++r) {
        int row = w * 32 + mf * 16 + g * 4 + r;
        int rb = row * 256;
        int swzp = (row & 7) << 4;
#pragma unroll
        for (int nf = 0; nf < 8; ++nf) {
          int addr = (rb + (nf * 16 + r16) * 2) ^ swzp;
          *(bf16*)(Pl + addr) = (bf16)s[mf][nf][r];
        }
      }
    __syncthreads();

#pragma unroll
    for (int ks = 0; ks < 4; ++ks) {
      bf16x8 pf[2];
#pragma unroll
      for (int mf = 0; mf < 2; ++mf) {
        int row = w * 32 + mf * 16 + r16;
        int addr = (row * 256 + ks * 64 + g * 16) ^ ((row & 7) << 4);
        pf[mf] = *(const bf16x8*)(Pl + addr);
      }
      bf16x8 vf[4];
#pragma unroll
      for (int hf = 0; hf < 4; ++hf)
        vf[hf] = *(const bf16x8*)&Vt[(hf * 16 + r16) * 128 + ks * 32 + g * 8];
#pragma unroll
      for (int mf = 0; mf < 2; ++mf)
#pragma unroll
        for (int hf = 0; hf < 4; ++hf)
          oacc[mf][hf] = MFMA16(pf[mf], vf[hf], oacc[mf][hf]);
    }
    __syncthreads();
  }

  int nth = t >> 2, ntw = t & 3;
#pragma unroll
  for (int mf = 0; mf < 2; ++mf)
#pragma unroll
    for (int r = 0; r < 4; ++r) {
      float inv = __builtin_amdgcn_rcpf(lrun[mf][r]);
      int tn = w * 32 + mf * 16 + g * 4 + r;
      int stok = (nth * 8 + (tn >> 4)) * 64 + ntw * 16 + (tn & 15);
#pragma unroll
      for (int hf = 0; hf < 4; ++hf) {
        int col = h * 64 + hf * 16 + r16;
        o_bf[((size_t)b * 4096 + stok) * 2048 + col] = (bf16)(oacc[mf][hf][r] * inv);
      }
    }
}

// ---------------- launcher ----------------
extern "C" void kernel_launch(void* const* d_in, const int* in_sizes, int n_in,
                              void* d_out, int out_size, void* d_ws, size_t ws_size,
                              hipStream_t stream) {
  const float* X = (const float*)d_in[0];
  const float* Wq = (const float*)d_in[1];
  const float* Wk = (const float*)d_in[2];
  const float* Wv = (const float*)d_in[3];
  const float* Wo = (const float*)d_in[4];
  float* out = (float*)d_out;
  char* ws = (char*)d_ws;
  if (ws_size < 159383552u) return;  // need ~159.4 MB scratch

  bf16* Xb  = (bf16*)(ws + 0);           // 33.5 MB, later reused as o_bf
  bf16* WT0 = (bf16*)(ws + 33554432u);   // 8.4 MB (WqT, later WoT)
  bf16* WT1 = (bf16*)(ws + 41943040u);   // WkT
  bf16* WT2 = (bf16*)(ws + 50331648u);   // WvT
  bf16* q_t = (bf16*)(ws + 58720256u);   // 33.5 MB
  bf16* k_t = (bf16*)(ws + 92274688u);   // 33.5 MB
  bf16* v_t = (bf16*)(ws + 125829120u);  // 33.5 MB
  bf16* o_bf = Xb;

  cast_x_kernel<<<16384, 256, 0, stream>>>(X, Xb);
  transpose_w_kernel<<<1024, 256, 0, stream>>>(Wq, WT0);
  transpose_w_kernel<<<1024, 256, 0, stream>>>(Wk, WT1);
  transpose_w_kernel<<<1024, 256, 0, stream>>>(Wv, WT2);
  gemm_qkv_kernel<<<768, 512, 0, stream>>>(Xb, WT0, WT1, WT2, q_t, k_t, v_t);
  attn_kernel<<<2048, 256, 0, stream>>>(q_t, k_t, v_t, o_bf);
  transpose_w_kernel<<<1024, 256, 0, stream>>>(Wo, WT0);
  gemm_out_kernel<<<256, 512, 0, stream>>>(o_bf, WT0, out);
}

// Round 6
// 504.595 us; speedup vs baseline: 1.0741x; 1.0741x over previous
//
#include <hip/hip_runtime.h>

typedef __bf16 bf16;
typedef __attribute__((ext_vector_type(8))) __bf16 bf16x8;
typedef __attribute__((ext_vector_type(4))) __bf16 bf16x4;
typedef __attribute__((ext_vector_type(4))) float f32x4;

#define MFMA16(a, b, c) __builtin_amdgcn_mfma_f32_16x16x32_bf16((a), (b), (c), 0, 0, 0)

__device__ __forceinline__ void gload16(const void* g, void* lds) {
  __builtin_amdgcn_global_load_lds(
      (__attribute__((address_space(1))) unsigned int*)(unsigned long long)g,
      (__attribute__((address_space(3))) unsigned int*)lds, 16, 0, 0);
}

// ---------------- cast X (fp32 -> bf16) ----------------
__global__ void __launch_bounds__(256) cast_x_kernel(const float* __restrict__ X,
                                                     bf16* __restrict__ Xb) {
  int i = (blockIdx.x * 256 + threadIdx.x) * 4;
  f32x4 v = *(const f32x4*)(X + i);
  bf16x4 o;
  o[0] = (bf16)v[0]; o[1] = (bf16)v[1]; o[2] = (bf16)v[2]; o[3] = (bf16)v[3];
  *(bf16x4*)(Xb + i) = o;
}

// ---------------- transpose + cast 3 weights in one launch: WT[n][k] = W[k][n] ----------------
__global__ void __launch_bounds__(256) transpose_w3_kernel(const float* __restrict__ Wq,
                                                           const float* __restrict__ Wk,
                                                           const float* __restrict__ Wv,
                                                           bf16* __restrict__ T0,
                                                           bf16* __restrict__ T1,
                                                           bf16* __restrict__ T2) {
  __shared__ float tile[64][65];
  int which = blockIdx.x >> 10;
  int bid = blockIdx.x & 1023;
  const float* W = which == 0 ? Wq : (which == 1 ? Wk : Wv);
  bf16* WT = which == 0 ? T0 : (which == 1 ? T1 : T2);
  int n0 = (bid & 31) * 64;
  int k0 = (bid >> 5) * 64;
  int tid = threadIdx.x;
  int r = tid >> 4;
  int c4 = (tid & 15) * 4;
#pragma unroll
  for (int i = 0; i < 4; ++i) {
    f32x4 v = *(const f32x4*)(W + (size_t)(k0 + r + i * 16) * 2048 + n0 + c4);
    tile[r + i * 16][c4 + 0] = v[0];
    tile[r + i * 16][c4 + 1] = v[1];
    tile[r + i * 16][c4 + 2] = v[2];
    tile[r + i * 16][c4 + 3] = v[3];
  }
  __syncthreads();
#pragma unroll
  for (int i = 0; i < 4; ++i) {
    int n = r + i * 16;
    bf16x4 o;
    o[0] = (bf16)tile[c4 + 0][n];
    o[1] = (bf16)tile[c4 + 1][n];
    o[2] = (bf16)tile[c4 + 2][n];
    o[3] = (bf16)tile[c4 + 3][n];
    *(bf16x4*)(WT + (size_t)(n0 + n) * 2048 + k0 + c4) = o;
  }
}

__global__ void __launch_bounds__(256) transpose_w_kernel(const float* __restrict__ W,
                                                          bf16* __restrict__ WT) {
  __shared__ float tile[64][65];
  int n0 = (blockIdx.x & 31) * 64;
  int k0 = (blockIdx.x >> 5) * 64;
  int tid = threadIdx.x;
  int r = tid >> 4;
  int c4 = (tid & 15) * 4;
#pragma unroll
  for (int i = 0; i < 4; ++i) {
    f32x4 v = *(const f32x4*)(W + (size_t)(k0 + r + i * 16) * 2048 + n0 + c4);
    tile[r + i * 16][c4 + 0] = v[0];
    tile[r + i * 16][c4 + 1] = v[1];
    tile[r + i * 16][c4 + 2] = v[2];
    tile[r + i * 16][c4 + 3] = v[3];
  }
  __syncthreads();
#pragma unroll
  for (int i = 0; i < 4; ++i) {
    int n = r + i * 16;
    bf16x4 o;
    o[0] = (bf16)tile[c4 + 0][n];
    o[1] = (bf16)tile[c4 + 1][n];
    o[2] = (bf16)tile[c4 + 2][n];
    o[3] = (bf16)tile[c4 + 3][n];
    *(bf16x4*)(WT + (size_t)(n0 + n) * 2048 + k0 + c4) = o;
  }
}

// ---------------- 256x256 GEMM core, 1-barrier/iter ring-3 pipeline (round-3 best) ----------------
__device__ __forceinline__ void gemm256_core(const bf16* __restrict__ Ag,
                                             const bf16* __restrict__ Bg,
                                             char* lds, f32x4 (&acc)[8][4]) {
  const int tid = threadIdx.x;
  const int lane = tid & 63, wid = tid >> 6;
  const int g = lane >> 4, r16 = lane & 15;
  const int wm = wid >> 2, wn = wid & 3;
  const int swz = ((g ^ ((r16 >> 1) & 3)) << 4);

  const int srow = wid * 32 + (lane >> 2);
  const int scol = ((lane & 3) ^ ((lane >> 3) & 3)) * 8;
  const bf16* gA = Ag + (size_t)srow * 2048 + scol;
  const bf16* gB = Bg + (size_t)srow * 2048 + scol;
  char* sA = lds + wid * 2048;
  char* sB = lds + 16384 + wid * 2048;

  const int arow0 = wm * 128 + r16;
  const int brow0 = wn * 64 + r16;

#define STAGE_A(bf_, tt_)                              \
  {                                                    \
    char* d_ = sA + (bf_) * 32768;                     \
    const bf16* s_ = gA + (size_t)(tt_) * 32;          \
    gload16(s_, d_);                                   \
    gload16(s_ + (size_t)16 * 2048, d_ + 1024);        \
  }
#define STAGE_B(bf_, tt_)                              \
  {                                                    \
    char* d_ = sB + (bf_) * 32768;                     \
    const bf16* s_ = gB + (size_t)(tt_) * 32;          \
    gload16(s_, d_);                                   \
    gload16(s_ + (size_t)16 * 2048, d_ + 1024);        \
  }

  STAGE_A(0, 0) STAGE_B(0, 0) STAGE_A(1, 1) STAGE_B(1, 1)
  asm volatile("s_waitcnt vmcnt(4)" ::: "memory");
  __builtin_amdgcn_s_barrier();
  __builtin_amdgcn_sched_barrier(0);

  int c = 0;
  for (int t = 0; t < 64; ++t) {
    const char* Ab = lds + c * 32768;
    const char* Bb = Ab + 16384;
    int sbuf = c + 2; if (sbuf >= 3) sbuf -= 3;

    bf16x8 bfr[4], af[8];
#pragma unroll
    for (int j = 0; j < 4; ++j)
      bfr[j] = *(const bf16x8*)(Bb + (brow0 + j * 16) * 64 + swz);
#pragma unroll
    for (int i = 0; i < 8; ++i)
      af[i] = *(const bf16x8*)(Ab + (arow0 + i * 16) * 64 + swz);

    if (t < 62) { STAGE_A(sbuf, t + 2) STAGE_B(sbuf, t + 2) }

#pragma unroll
    for (int i = 0; i < 8; ++i)
#pragma unroll
      for (int j = 0; j < 4; ++j)
        acc[i][j] = MFMA16(af[i], bfr[j], acc[i][j]);

    if (t < 62) {
      asm volatile("s_waitcnt vmcnt(4)" ::: "memory");
    } else if (t == 62) {
      asm volatile("s_waitcnt vmcnt(0)" ::: "memory");
    }
    __builtin_amdgcn_s_barrier();
    __builtin_amdgcn_sched_barrier(0);

    c += 1; if (c >= 3) c -= 3;
  }
#undef STAGE_A
#undef STAGE_B
}

// ---------------- QKV projection GEMM (256^2 tile), scatter to tile-major ----------------
__global__ void __launch_bounds__(512, 2) gemm_qkv_kernel(
    const bf16* __restrict__ Xb, const bf16* __restrict__ W0, const bf16* __restrict__ W1,
    const bf16* __restrict__ W2, bf16* __restrict__ q_t, bf16* __restrict__ k_t,
    bf16* __restrict__ v_t) {
  __shared__ char lds[98304];
  int bid = blockIdx.x;
  int xcd = bid & 7, idx = bid >> 3;          // 768 = 8 XCD chunks of 96
  int by = xcd * 4 + idx / 24, bx = idx % 24; // m-major within chunk for L2 reuse
  int which = bx >> 3;
  int m0 = by * 256, n0 = (bx & 7) * 256;
  const bf16* W = which == 0 ? W0 : (which == 1 ? W1 : W2);

  f32x4 acc[8][4] = {};
  gemm256_core(Xb + (size_t)m0 * 2048, W + (size_t)n0 * 2048, lds, acc);

  int lane = threadIdx.x & 63, wid = threadIdx.x >> 6;
  int g = lane >> 4, r16 = lane & 15;
  int wm = wid >> 2, wn = wid & 3;
#pragma unroll
  for (int i = 0; i < 8; ++i) {
#pragma unroll
    for (int r = 0; r < 4; ++r) {
      int m = m0 + wm * 128 + i * 16 + g * 4 + r;
      int b = m >> 12, s = m & 4095;
      int hg = s >> 6, wg = s & 63;
      int t = ((hg >> 3) << 2) + (wg >> 4);
      int tn = ((hg & 7) << 4) + (wg & 15);
#pragma unroll
      for (int j = 0; j < 4; ++j) {
        int n = n0 + wn * 64 + j * 16 + r16;
        int h = n >> 6, hd = n & 63;
        float val = acc[i][j][r];
        size_t base = ((size_t)(b * 32 + h) * 32 + t);
        if (which == 0)
          q_t[(base * 128 + tn) * 64 + hd] = (bf16)(val * 0.125f);
        else if (which == 1)
          k_t[(base * 128 + tn) * 64 + hd] = (bf16)val;
        else
          v_t[(base * 64 + hd) * 128 + tn] = (bf16)val;
      }
    }
  }
}

// ---------------- output GEMM: out = o_bf @ Wo, fp32 row-major ----------------
__global__ void __launch_bounds__(512, 2) gemm_out_kernel(const bf16* __restrict__ A,
                                                          const bf16* __restrict__ W,
                                                          float* __restrict__ C) {
  __shared__ char lds[98304];
  int bid = blockIdx.x;
  int xcd = bid & 7, idx = bid >> 3;         // 256 = 8 chunks of 32
  int by = xcd * 4 + idx / 8, bx = idx & 7;
  int m0 = by * 256, n0 = bx * 256;

  f32x4 acc[8][4] = {};
  gemm256_core(A + (size_t)m0 * 2048, W + (size_t)n0 * 2048, lds, acc);

  int lane = threadIdx.x & 63, wid = threadIdx.x >> 6;
  int g = lane >> 4, r16 = lane & 15;
  int wm = wid >> 2, wn = wid & 3;
#pragma unroll
  for (int i = 0; i < 8; ++i)
#pragma unroll
    for (int j = 0; j < 4; ++j)
#pragma unroll
      for (int r = 0; r < 4; ++r) {
        int m = m0 + wm * 128 + i * 16 + g * 4 + r;
        int n = n0 + wn * 64 + j * 16 + r16;
        C[(size_t)m * 2048 + n] = acc[i][j][r];
      }
}

// ---------------- block-sparse tile attention, XCD-chunked bh placement ----------------
// XCD x owns bh in [8x, 8x+8): bh = (bid&7)*8 + (bid>>8), t = (bid>>3)&31.
// All 32 query tiles of one bh run near-concurrently on one XCD -> its 1MB
// K/V set stays in that XCD's L2 instead of being filled into all 8 L2s.
__global__ void __launch_bounds__(256) attn_kernel(const bf16* __restrict__ q_t,
                                                   const bf16* __restrict__ k_t,
                                                   const bf16* __restrict__ v_t,
                                                   bf16* __restrict__ o_bf) {
  __shared__ char Pl[128 * 256];  // P tile, bf16, XOR-swizzled rows of 256B
  int bid = blockIdx.x;
  int bh = (bid & 7) * 8 + (bid >> 8);
  int t = (bid >> 3) & 31;
  int h = bh & 31, b = bh >> 5;
  int tid = threadIdx.x, w = tid >> 6, lane = tid & 63;
  int g = lane >> 4, r16 = lane & 15;

  const size_t qoff = ((size_t)bh * 32 + t) * (128 * 64);
  bf16x8 qf[2][2];
#pragma unroll
  for (int mf = 0; mf < 2; ++mf)
#pragma unroll
    for (int kf = 0; kf < 2; ++kf)
      qf[mf][kf] = *(const bf16x8*)&q_t[qoff + (size_t)(w * 32 + mf * 16 + r16) * 64 + kf * 32 + g * 8];

  f32x4 oacc[2][4] = {};
  float mrun[2][4], lrun[2][4];
#pragma unroll
  for (int mf = 0; mf < 2; ++mf)
#pragma unroll
    for (int r = 0; r < 4; ++r) { mrun[mf][r] = -1e30f; lrun[mf][r] = 0.f; }

  int qh = t >> 2, qw = t & 3;
  int ch = qh < 1 ? 1 : (qh > 7 ? 7 : qh);
  int cw = qw < 1 ? 1 : (qw > 3 ? 3 : qw);

  for (int c = 0; c < 4; ++c) {
    int vt = (ch - 1 + (c >> 1)) * 4 + (cw - 1 + (c & 1));
    const bf16* Kt = k_t + ((size_t)bh * 32 + vt) * (128 * 64);
    const bf16* Vt = v_t + ((size_t)bh * 32 + vt) * (128 * 64);

    f32x4 s[2][8];
#pragma unroll
    for (int nf = 0; nf < 8; ++nf) {
      bf16x8 kf0 = *(const bf16x8*)&Kt[(nf * 16 + r16) * 64 + g * 8];
      bf16x8 kf1 = *(const bf16x8*)&Kt[(nf * 16 + r16) * 64 + 32 + g * 8];
#pragma unroll
      for (int mf = 0; mf < 2; ++mf) {
        f32x4 z = {};
        z = MFMA16(qf[mf][0], kf0, z);
        z = MFMA16(qf[mf][1], kf1, z);
        s[mf][nf] = z;
      }
    }

#pragma unroll
    for (int mf = 0; mf < 2; ++mf) {
#pragma unroll
      for (int r = 0; r < 4; ++r) {
        float mx = s[mf][0][r];
#pragma unroll
        for (int nf = 1; nf < 8; ++nf) mx = fmaxf(mx, s[mf][nf][r]);
        mx = fmaxf(mx, __shfl_xor(mx, 1));
        mx = fmaxf(mx, __shfl_xor(mx, 2));
        mx = fmaxf(mx, __shfl_xor(mx, 4));
        mx = fmaxf(mx, __shfl_xor(mx, 8));
        float mold = mrun[mf][r];
        float mnew = fmaxf(mold, mx);
        float sc = __expf(mold - mnew);
        mrun[mf][r] = mnew;
        float ps = 0.f;
#pragma unroll
        for (int nf = 0; nf < 8; ++nf) {
          float p = __expf(s[mf][nf][r] - mnew);
          s[mf][nf][r] = p;
          ps += p;
        }
        ps += __shfl_xor(ps, 1);
        ps += __shfl_xor(ps, 2);
        ps += __shfl_xor(ps, 4);
        ps += __shfl_xor(ps, 8);
        lrun[mf][r] = lrun[mf][r] * sc + ps;
#pragma unroll
        for (int hf = 0; hf < 4; ++hf) oacc[mf][hf][r] *= sc;
      }
    }

#pragma unroll
    for (int mf = 0; mf < 2; ++mf)
#pragma unroll
      for (int r = 0; r < 4; ++r) {
        int row = w * 32 + mf * 16 + g * 4 + r;
        int rb = row * 256;
        int swzp = (row & 7) << 4;
#pragma unroll
        for (int nf = 0; nf < 8; ++nf) {
          int addr = (rb + (nf * 16 + r16) * 2) ^ swzp;
          *(bf16*)(Pl + addr) = (bf16)s[mf][nf][r];
        }
      }
    __syncthreads();

#pragma unroll
    for (int ks = 0; ks < 4; ++ks) {
      bf16x8 pf[2];
#pragma unroll
      for (int mf = 0; mf < 2; ++mf) {
        int row = w * 32 + mf * 16 + r16;
        int addr = (row * 256 + ks * 64 + g * 16) ^ ((row & 7) << 4);
        pf[mf] = *(const bf16x8*)(Pl + addr);
      }
      bf16x8 vf[4];
#pragma unroll
      for (int hf = 0; hf < 4; ++hf)
        vf[hf] = *(const bf16x8*)&Vt[(hf * 16 + r16) * 128 + ks * 32 + g * 8];
#pragma unroll
      for (int mf = 0; mf < 2; ++mf)
#pragma unroll
        for (int hf = 0; hf < 4; ++hf)
          oacc[mf][hf] = MFMA16(pf[mf], vf[hf], oacc[mf][hf]);
    }
    __syncthreads();
  }

  int nth = t >> 2, ntw = t & 3;
#pragma unroll
  for (int mf = 0; mf < 2; ++mf)
#pragma unroll
    for (int r = 0; r < 4; ++r) {
      float inv = __builtin_amdgcn_rcpf(lrun[mf][r]);
      int tn = w * 32 + mf * 16 + g * 4 + r;
      int stok = (nth * 8 + (tn >> 4)) * 64 + ntw * 16 + (tn & 15);
#pragma unroll
      for (int hf = 0; hf < 4; ++hf) {
        int col = h * 64 + hf * 16 + r16;
        o_bf[((size_t)b * 4096 + stok) * 2048 + col] = (bf16)(oacc[mf][hf][r] * inv);
      }
    }
}

// ---------------- launcher ----------------
extern "C" void kernel_launch(void* const* d_in, const int* in_sizes, int n_in,
                              void* d_out, int out_size, void* d_ws, size_t ws_size,
                              hipStream_t stream) {
  const float* X = (const float*)d_in[0];
  const float* Wq = (const float*)d_in[1];
  const float* Wk = (const float*)d_in[2];
  const float* Wv = (const float*)d_in[3];
  const float* Wo = (const float*)d_in[4];
  float* out = (float*)d_out;
  char* ws = (char*)d_ws;
  if (ws_size < 159383552u) return;  // need ~159.4 MB scratch

  bf16* Xb  = (bf16*)(ws + 0);           // 33.5 MB, later reused as o_bf
  bf16* WT0 = (bf16*)(ws + 33554432u);   // 8.4 MB (WqT, later WoT)
  bf16* WT1 = (bf16*)(ws + 41943040u);   // WkT
  bf16* WT2 = (bf16*)(ws + 50331648u);   // WvT
  bf16* q_t = (bf16*)(ws + 58720256u);   // 33.5 MB
  bf16* k_t = (bf16*)(ws + 92274688u);   // 33.5 MB
  bf16* v_t = (bf16*)(ws + 125829120u);  // 33.5 MB
  bf16* o_bf = Xb;

  cast_x_kernel<<<16384, 256, 0, stream>>>(X, Xb);
  transpose_w3_kernel<<<3072, 256, 0, stream>>>(Wq, Wk, Wv, WT0, WT1, WT2);
  gemm_qkv_kernel<<<768, 512, 0, stream>>>(Xb, WT0, WT1, WT2, q_t, k_t, v_t);
  attn_kernel<<<2048, 256, 0, stream>>>(q_t, k_t, v_t, o_bf);
  transpose_w_kernel<<<1024, 256, 0, stream>>>(Wo, WT0);
  gemm_out_kernel<<<256, 512, 0, stream>>>(o_bf, WT0, out);
}